// Round 10
// baseline (1423.135 us; speedup 1.0000x reference)
//
#include <hip/hip_runtime.h>
#include <math.h>

// ---------------- device helpers ----------------

__device__ __forceinline__ float elu_f(float x) {
    return x > 0.f ? x : expm1f(x);
}

// ---------------- node MLP ----------------

__global__ void mlp_kernel(const float* __restrict__ x,
                           const float* __restrict__ A, const float* __restrict__ ab,
                           const float* __restrict__ B, const float* __restrict__ bb,
                           float* __restrict__ out, int n) {
    __shared__ float sA[23 * 23], sB[23 * 23], sa[23], sb[23];
    for (int t = threadIdx.x; t < 23 * 23; t += blockDim.x) { sA[t] = A[t]; sB[t] = B[t]; }
    if (threadIdx.x < 23) { sa[threadIdx.x] = ab[threadIdx.x]; sb[threadIdx.x] = bb[threadIdx.x]; }
    __syncthreads();
    int i = blockIdx.x * blockDim.x + threadIdx.x;
    if (i >= n) return;
    float xi[23], h1[23];
    #pragma unroll
    for (int j = 0; j < 23; j++) xi[j] = x[(size_t)i * 23 + j];
    #pragma unroll
    for (int o = 0; o < 23; o++) {
        float acc = sa[o];
        #pragma unroll
        for (int j = 0; j < 23; j++) acc = fmaf(xi[j], sA[j * 23 + o], acc);
        h1[o] = elu_f(acc);
    }
    #pragma unroll
    for (int o = 0; o < 23; o++) {
        float acc = sb[o];
        #pragma unroll
        for (int j = 0; j < 23; j++) acc = fmaf(h1[j], sB[j * 23 + o], acc);
        out[(size_t)i * 23 + o] = elu_f(acc);
    }
}

// ---------------- bank-aligned multi-output projection GEMM ----------------
// CONFIG 1 (conv1): IN=23,  OUTW=192, cols = [kv-pair 0..383 | s 384..575], NT=384, CPT=12
// CONFIG 2 (conv2): IN=192, OUTW=64,  cols = [q 0..63 | kv-pair 64..191 | s 192..255], NT=256, CPT=8
// kv-pair virtual column 2c -> Wk col c, 2c+1 -> Wv col c  => row-major stores yield
// pair-interleaved kv rows [(k_c,v_c)...] directly.
// Thread map: ng=tid%8 (nodes 8ng..8ng+7), cg=tid/8 (cols CPT*cg..): sA reads are
// 8-lane broadcasts; sB reads = 8 consecutive-cg float4 addrs/wave -> conflict-free.
template<int CONFIG>
__global__ void proj_gemm_kernel(const float* __restrict__ in, int n,
    const float* __restrict__ Wq, const float* __restrict__ qb,
    const float* __restrict__ Wk, const float* __restrict__ kb,
    const float* __restrict__ Wv, const float* __restrict__ vb,
    const float* __restrict__ Ws, const float* __restrict__ sb,
    float* __restrict__ qout, float* __restrict__ kvout, float* __restrict__ sout) {
    constexpr int IN   = (CONFIG == 1) ? 23 : 192;
    constexpr int Kc   = (CONFIG == 1) ? 23 : 32;
    constexpr int OUTW = (CONFIG == 1) ? 192 : 64;
    constexpr int WTOT = (CONFIG == 1) ? 576 : 256;
    constexpr int NT   = (CONFIG == 1) ? 384 : 256;
    constexpr int CPT  = (CONFIG == 1) ? 12 : 8;
    constexpr int BN   = 64;
    constexpr int SAW  = BN + 4;
    __shared__ float sA[Kc][SAW];
    __shared__ float sB[Kc][WTOT];

    const int tid = threadIdx.x;
    const int ng = tid & 7;          // node group
    const int cg = tid >> 3;         // col group
    const int node0 = blockIdx.x * BN;
    const int c0 = CPT * cg;

    // column -> (W, wcol) mapping for staging/bias
    auto wmap = [&](int c, const float*& W, const float*& b, int& wc) {
        if constexpr (CONFIG == 1) {
            if (c < 384) { W = (c & 1) ? Wv : Wk; b = (c & 1) ? vb : kb; wc = c >> 1; }
            else         { W = Ws; b = sb; wc = c - 384; }
        } else {
            if (c < 64)       { W = Wq; b = qb; wc = c; }
            else if (c < 192) { int u = c - 64; W = (u & 1) ? Wv : Wk; b = (u & 1) ? vb : kb; wc = u >> 1; }
            else              { W = Ws; b = sb; wc = c - 192; }
        }
    };

    float acc[8][CPT];
    #pragma unroll
    for (int ci = 0; ci < CPT; ci++) {
        const float *W, *b; int wc;
        wmap(c0 + ci, W, b, wc);
        float bv = b[wc];
        #pragma unroll
        for (int ni = 0; ni < 8; ni++) acc[ni][ci] = bv;
    }

    for (int k0 = 0; k0 < IN; k0 += Kc) {
        for (int t = tid; t < Kc * BN; t += NT) {
            int j = t / BN, nn = t - j * BN;
            int g = node0 + nn;
            sA[j][nn] = (g < n) ? in[(size_t)g * IN + k0 + j] : 0.f;
        }
        for (int t = tid; t < Kc * WTOT; t += NT) {
            int j = t / WTOT, c = t - j * WTOT;
            const float *W, *b; int wc;
            wmap(c, W, b, wc);
            sB[j][c] = W[(size_t)(k0 + j) * OUTW + wc];
        }
        __syncthreads();
        #pragma unroll 4
        for (int j = 0; j < Kc; j++) {
            float4 a0 = *(const float4*)&sA[j][8 * ng];
            float4 a1 = *(const float4*)&sA[j][8 * ng + 4];
            float av[8] = {a0.x, a0.y, a0.z, a0.w, a1.x, a1.y, a1.z, a1.w};
            float bv[CPT];
            #pragma unroll
            for (int i = 0; i < CPT / 4; i++) {
                float4 t4 = *(const float4*)&sB[j][c0 + 4 * i];
                bv[4 * i] = t4.x; bv[4 * i + 1] = t4.y; bv[4 * i + 2] = t4.z; bv[4 * i + 3] = t4.w;
            }
            #pragma unroll
            for (int ni = 0; ni < 8; ni++)
                #pragma unroll
                for (int ci = 0; ci < CPT; ci++)
                    acc[ni][ci] = fmaf(av[ni], bv[ci], acc[ni][ci]);
        }
        __syncthreads();
    }

    // epilogue: thread's cols live in exactly one output buffer
    float* obase; int ostride, ocoff;
    if constexpr (CONFIG == 1) {
        if (c0 < 384) { obase = kvout; ostride = 384; ocoff = c0; }
        else          { obase = sout;  ostride = 192; ocoff = c0 - 384; }
    } else {
        if (c0 < 64)       { obase = qout;  ostride = 64;  ocoff = c0; }
        else if (c0 < 192) { obase = kvout; ostride = 128; ocoff = c0 - 64; }
        else               { obase = sout;  ostride = 64;  ocoff = c0 - 192; }
    }
    #pragma unroll
    for (int ni = 0; ni < 8; ni++) {
        int g = node0 + 8 * ng + ni;
        if (g >= n) continue;
        float* op = obase + (size_t)g * ostride + ocoff;
        #pragma unroll
        for (int i = 0; i < CPT / 4; i++)
            *(float4*)(op + 4 * i) = make_float4(acc[ni][4 * i], acc[ni][4 * i + 1],
                                                 acc[ni][4 * i + 2], acc[ni][4 * i + 3]);
    }
}

// ---------------- CSR build ----------------

__global__ void zero2_kernel(int* __restrict__ a, int* __restrict__ b, int n) {
    int i = blockIdx.x * blockDim.x + threadIdx.x;
    if (i < n) { a[i] = 0; b[i] = 0; }
}

__global__ void count_kernel(const int* __restrict__ dst, int* __restrict__ cnt, int nE) {
    int e = blockIdx.x * blockDim.x + threadIdx.x;
    if (e < nE) atomicAdd(&cnt[dst[e]], 1);
}

__global__ void scan_block_kernel(int* __restrict__ cnt, int* __restrict__ bsum, int n) {
    __shared__ int sdat[256];
    int i = blockIdx.x * 256 + threadIdx.x;
    int v = (i < n) ? cnt[i] : 0;
    sdat[threadIdx.x] = v;
    __syncthreads();
    for (int off = 1; off < 256; off <<= 1) {
        int t = (threadIdx.x >= (unsigned)off) ? sdat[threadIdx.x - off] : 0;
        __syncthreads();
        sdat[threadIdx.x] += t;
        __syncthreads();
    }
    if (i < n) cnt[i] = sdat[threadIdx.x] - v;
    if (threadIdx.x == 255) bsum[blockIdx.x] = sdat[255];
}

__global__ void scan_bsum_kernel(int* __restrict__ bsum, int nb) {
    __shared__ int s[1024];
    int i = threadIdx.x;
    int v = (i < nb) ? bsum[i] : 0;
    s[i] = v;
    __syncthreads();
    for (int off = 1; off < 1024; off <<= 1) {
        int t = (i >= off) ? s[i - off] : 0;
        __syncthreads();
        s[i] += t;
        __syncthreads();
    }
    if (i < nb) bsum[i] = s[i] - v;
}

__global__ void finalize_rp_kernel(const int* __restrict__ cnt, const int* __restrict__ bsum,
                                   int* __restrict__ rp, int n, int nE) {
    int i = blockIdx.x * blockDim.x + threadIdx.x;
    if (i < n) rp[i] = cnt[i] + bsum[i >> 8];
    if (i == n) rp[n] = nE;
}

__global__ void scatter_kernel(const int* __restrict__ src, const int* __restrict__ dst,
                               const int* __restrict__ rp, int* __restrict__ cur,
                               int* __restrict__ srcS, int* __restrict__ eidS, int nE) {
    int e = blockIdx.x * blockDim.x + threadIdx.x;
    if (e >= nE) return;
    int d = dst[e];
    int pos = rp[d] + atomicAdd(&cur[d], 1);
    srcS[pos] = src[e];
    eidS[pos] = e;
}

// ---------------- fused TransformerConv (one wave per dst node) ----------------
// kv: channel-pair interleaved fp32 [n][HC][2] = [(k_c,v_c)...]; skip pre-stored in out.
// 2-wide unrolled edge loop, branchless clamped depth-2 prefetch, pairwise
// online-softmax update (odd tail handled via z=-INF -> exp=0 no-op).
template<int IN, int C, bool QMAT, bool DOELU>
__global__ void conv_fused_kernel(const float* __restrict__ feat,
                                  const float* __restrict__ Wq, const float* __restrict__ qb,
                                  const float* __restrict__ kv,
                                  const float* __restrict__ qmat,
                                  const float* __restrict__ ea, const float* __restrict__ We,
                                  const int* __restrict__ rp, const int* __restrict__ srcS,
                                  const int* __restrict__ eidS,
                                  float* __restrict__ out, int n, float scale) {
    constexpr int HC = 8 * C;
    constexpr int CPL = HC / 64;
    constexpr int KVROW = 2 * HC;
    const int lane = threadIdx.x & 63;
    const int d = blockIdx.x * (blockDim.x >> 6) + (threadIdx.x >> 6);
    if (d >= n) return;
    const int ch0 = lane * CPL;

    float we[7][CPL];
    #pragma unroll
    for (int j = 0; j < 7; j++)
        #pragma unroll
        for (int c = 0; c < CPL; c++) we[j][c] = We[j * HC + ch0 + c];

    float* op = out + (size_t)d * HC + ch0;
    float sk[CPL], q[CPL];
    #pragma unroll
    for (int c = 0; c < CPL; c++) sk[c] = op[c];       // pre-stored skip
    if constexpr (QMAT) {
        const float* qp = qmat + (size_t)d * HC + ch0;
        #pragma unroll
        for (int c = 0; c < CPL; c++) q[c] = qp[c];
    } else {
        #pragma unroll
        for (int c = 0; c < CPL; c++) q[c] = qb[ch0 + c];
        const float* fd = feat + (size_t)d * IN;
        for (int j = 0; j < IN; j++) {
            float f = fd[j];
            #pragma unroll
            for (int c = 0; c < CPL; c++)
                q[c] = fmaf(f, Wq[(size_t)j * HC + ch0 + c], q[c]);
        }
    }

    float m = -INFINITY, l = 0.f, acc[CPL];
    #pragma unroll
    for (int c = 0; c < CPL; c++) acc[c] = 0.f;

    const int p0 = rp[d], p1 = rp[d + 1];
    if (p0 < p1) {
        auto loadEdge = [&](int p, float* kc, float* vc, float* ev) {
            int s = srcS[p], eid = eidS[p];
            const float* pb = kv + (size_t)s * KVROW + 2 * ch0;
            #pragma unroll
            for (int c = 0; c < CPL; c++) {
                float2 t = *(const float2*)(pb + 2 * c);
                kc[c] = t.x; vc[c] = t.y;
            }
            const float* ep = ea + (size_t)eid * 7;
            #pragma unroll
            for (int j = 0; j < 7; j++) ev[j] = ep[j];
        };
        auto logitv = [&](const float* kc, const float* vc, const float* ev, float* vv) {
            float part = 0.f;
            #pragma unroll
            for (int c = 0; c < CPL; c++) {
                float ec = 0.f;
                #pragma unroll
                for (int j = 0; j < 7; j++) ec = fmaf(ev[j], we[j][c], ec);
                part = fmaf(q[c], kc[c] + ec, part);
                vv[c] = vc[c] + ec;
            }
            part += __shfl_xor(part, 1);
            part += __shfl_xor(part, 2);
            part += __shfl_xor(part, 4);
            return part * scale;
        };

        const int pL = p1 - 1;
        float k0a[CPL], v0a[CPL], e0a[7], k1a[CPL], v1a[CPL], e1a[7];
        loadEdge(p0, k0a, v0a, e0a);
        loadEdge((p0 + 1 < p1) ? p0 + 1 : pL, k1a, v1a, e1a);

        for (int p = p0; p < p1; p += 2) {
            float k2a[CPL], v2a[CPL], e2a[7], k3a[CPL], v3a[CPL], e3a[7];
            loadEdge((p + 2 < p1) ? p + 2 : pL, k2a, v2a, e2a);   // branchless prefetch
            loadEdge((p + 3 < p1) ? p + 3 : pL, k3a, v3a, e3a);

            float vv0[CPL], vv1[CPL];
            float z0 = logitv(k0a, v0a, e0a, vv0);
            float z1 = logitv(k1a, v1a, e1a, vv1);
            if (p + 1 >= p1) z1 = -INFINITY;            // odd tail -> no-op

            float mn = fmaxf(m, fmaxf(z0, z1));
            float rs  = expf(m - mn);
            float pw0 = expf(z0 - mn);
            float pw1 = expf(z1 - mn);
            l = fmaf(l, rs, pw0 + pw1);
            #pragma unroll
            for (int c = 0; c < CPL; c++)
                acc[c] = fmaf(acc[c], rs, fmaf(pw0, vv0[c], pw1 * vv1[c]));
            m = mn;

            #pragma unroll
            for (int c = 0; c < CPL; c++) {
                k0a[c] = k2a[c]; v0a[c] = v2a[c];
                k1a[c] = k3a[c]; v1a[c] = v3a[c];
            }
            #pragma unroll
            for (int j = 0; j < 7; j++) { e0a[j] = e2a[j]; e1a[j] = e3a[j]; }
        }
    }
    float invl = (l > 0.f) ? 1.f / l : 0.f;
    #pragma unroll
    for (int c = 0; c < CPL; c++) {
        float r = sk[c] + acc[c] * invl;
        op[c] = DOELU ? elu_f(r) : r;
    }
}

// ---------------- head ----------------
__global__ void head_kernel(const float* __restrict__ h, const float* __restrict__ W1,
                            const float* __restrict__ b1, const float* __restrict__ W2,
                            const float* __restrict__ b2, float* __restrict__ out, int n) {
    __shared__ float sW1[64 * 20], sb1[20], sW2[20], sb2;
    for (int t = threadIdx.x; t < 64 * 20; t += blockDim.x) sW1[t] = W1[t];
    if (threadIdx.x < 20) { sb1[threadIdx.x] = b1[threadIdx.x]; sW2[threadIdx.x] = W2[threadIdx.x]; }
    if (threadIdx.x == 0) sb2 = b2[0];
    __syncthreads();
    int i = blockIdx.x * blockDim.x + threadIdx.x;
    if (i >= n) return;
    float hv[64];
    const float* hp = h + (size_t)i * 64;
    #pragma unroll
    for (int j = 0; j < 64; j++) hv[j] = elu_f(hp[j]);
    float acc2 = sb2;
    for (int o = 0; o < 20; o++) {
        float a = sb1[o];
        #pragma unroll
        for (int j = 0; j < 64; j++) a = fmaf(hv[j], sW1[j * 20 + o], a);
        acc2 = fmaf(elu_f(a), sW2[o], acc2);
    }
    out[i] = acc2;
}

__global__ void zero_out_kernel(float* __restrict__ out, int n) {
    int i = blockIdx.x * blockDim.x + threadIdx.x;
    if (i < n) out[i] = 0.f;
}

// ---------------- launcher ----------------

extern "C" void kernel_launch(void* const* d_in, const int* in_sizes, int n_in,
                              void* d_out, int out_size, void* d_ws, size_t ws_size,
                              hipStream_t stream) {
    const float* x   = (const float*)d_in[0];
    const int*   ei  = (const int*)d_in[1];
    const float* ea  = (const float*)d_in[2];
    const float* Aw  = (const float*)d_in[3];
    const float* Ab  = (const float*)d_in[4];
    const float* Bw  = (const float*)d_in[5];
    const float* Bb  = (const float*)d_in[6];
    const float* q1w = (const float*)d_in[7];  const float* q1b = (const float*)d_in[8];
    const float* k1w = (const float*)d_in[9];  const float* k1b = (const float*)d_in[10];
    const float* v1w = (const float*)d_in[11]; const float* v1b = (const float*)d_in[12];
    const float* e1w = (const float*)d_in[13];
    const float* s1w = (const float*)d_in[14]; const float* s1b = (const float*)d_in[15];
    const float* q2w = (const float*)d_in[16]; const float* q2b = (const float*)d_in[17];
    const float* k2w = (const float*)d_in[18]; const float* k2b = (const float*)d_in[19];
    const float* v2w = (const float*)d_in[20]; const float* v2b = (const float*)d_in[21];
    const float* e2w = (const float*)d_in[22];
    const float* s2w = (const float*)d_in[23]; const float* s2b = (const float*)d_in[24];
    const float* l1w = (const float*)d_in[25]; const float* l1b = (const float*)d_in[26];
    const float* l2w = (const float*)d_in[27]; const float* l2b = (const float*)d_in[28];

    const int n  = in_sizes[0] / 23;
    const int nE = in_sizes[1] / 2;
    const int* src = ei;
    const int* dst = ei + nE;
    float* out = (float*)d_out;
    const int B = 256;
    const int nb = (n + 255) / 256;

    // ---- workspace layout (float units); total = 599n floats + ints ≈ 247.2 MB ----
    size_t fl_h1 = ((size_t)n * 23 + 3) & ~(size_t)3;
    size_t fl_o1 = (size_t)n * 192;
    size_t fl_kv = (size_t)n * 384;   // kv1; conv2 reuses: kv2(128n)+q2(64n)+o2(64n)
    size_t ints_total = ((size_t)n + 1) + n + n + 1024 + (size_t)nE + (size_t)nE;
    size_t need_bytes = (fl_h1 + fl_o1 + fl_kv) * 4 + ints_total * 4;

    if (ws_size < need_bytes || nb > 1024) {
        zero_out_kernel<<<(out_size + B - 1) / B, B, 0, stream>>>(out, out_size);
        return;
    }

    float* ws = (float*)d_ws;
    size_t off = 0;
    float* h1    = ws + off; off += fl_h1;
    float* o1    = ws + off; off += fl_o1;
    float* kvreg = ws + off; off += fl_kv;
    int* ip = (int*)(ws + off);
    int* rp   = ip; ip += (size_t)n + 1;
    int* cnt  = ip; ip += n;
    int* cur  = ip; ip += n;
    int* bsum = ip; ip += 1024;
    int* srcS = ip; ip += nE;
    int* eidS = ip; ip += nE;

    float* kv1   = kvreg;                          // n*384 floats, channel-pair interleaved
    float* kv2   = kvreg;                          // n*128 floats (reuse after conv1)
    float* q2buf = kvreg + (size_t)n * 128;        // n*64
    float* o2    = kvreg + (size_t)n * 192;        // n*64

    const float sc1 = 1.0f / sqrtf(24.0f);
    const float sc2 = 1.0f / sqrtf(8.0f);
    const float* np = nullptr;
    float* npw = nullptr;

    // ---- CSR build ----
    zero2_kernel<<<(n + B - 1) / B, B, 0, stream>>>(cnt, cur, n);
    count_kernel<<<(nE + B - 1) / B, B, 0, stream>>>(dst, cnt, nE);
    scan_block_kernel<<<nb, 256, 0, stream>>>(cnt, bsum, n);
    scan_bsum_kernel<<<1, 1024, 0, stream>>>(bsum, nb);
    finalize_rp_kernel<<<(n + 1 + B - 1) / B, B, 0, stream>>>(cnt, bsum, rp, n, nE);
    scatter_kernel<<<(nE + B - 1) / B, B, 0, stream>>>(src, dst, rp, cur, srcS, eidS, nE);

    // ---- node MLP ----
    mlp_kernel<<<(n + B - 1) / B, B, 0, stream>>>(x, Aw, Ab, Bw, Bb, h1, n);

    const int gproj = (n + 63) / 64;

    // ---- conv1: k,v -> kv1 (pair-interleaved), skip -> o1; fused edge phase ----
    proj_gemm_kernel<1><<<gproj, 384, 0, stream>>>(
        h1, n, np, np, k1w, k1b, v1w, v1b, s1w, s1b,
        npw, kv1, o1);
    conv_fused_kernel<23, 24, false, true><<<(n + 3) / 4, 256, 0, stream>>>(
        h1, q1w, q1b, kv1, np, ea, e1w, rp, srcS, eidS, o1, n, sc1);

    // ---- conv2: q->q2buf, k,v->kv2 (pair-interleaved), skip->o2; fused edge phase ----
    proj_gemm_kernel<2><<<gproj, 256, 0, stream>>>(
        o1, n, q2w, q2b, k2w, k2b, v2w, v2b, s2w, s2b,
        q2buf, kv2, o2);
    conv_fused_kernel<192, 8, true, false><<<(n + 3) / 4, 256, 0, stream>>>(
        o1, q2w, q2b, kv2, q2buf, ea, e2w, rp, srcS, eidS, o2, n, sc2);

    // ---- head ----
    head_kernel<<<(n + B - 1) / B, B, 0, stream>>>(o2, l1w, l1b, l2w, l2b, out, n);
}